// Round 7
// baseline (9718.866 us; speedup 1.0000x reference)
//
#include <hip/hip_runtime.h>
#include <hip/hip_bf16.h>
#include <stdint.h>
#include <stddef.h>

#define B_SZ   4096
#define U_SZ   1024
#define SEQ    5
#define TSTEPS 200
#define STEPS  204          // 5 warmup + 199 decode LSTM steps

typedef __bf16 bf16_t;
typedef __bf16 bf16x8 __attribute__((ext_vector_type(8)));
typedef float  f32x4  __attribute__((ext_vector_type(4)));

#define AS1 __attribute__((address_space(1)))
#define AS3 __attribute__((address_space(3)))

#define LOAD_LDS16(gp, lp) \
    __builtin_amdgcn_global_load_lds((const AS1 unsigned int*)(gp), \
                                     (AS3 unsigned int*)(lp), 16, 0, 0)

__device__ __forceinline__ float fsig(float x) {
    return 1.0f / (1.0f + __expf(-x));
}
__device__ __forceinline__ float ftanh(float x) {
    x = fminf(fmaxf(x, -15.0f), 15.0f);
    float e = __expf(2.0f * x);
    return (e - 1.0f) / (e + 1.0f);
}

// ---------------------------------------------------------------------------
// Pack R (1024 x 4096 fp32 row-major) into bf16 panels for BK=32 staging:
//   Rp[ub:32][kb:32][c:128][slot:4][e:8]
//   stored (phys) slot holds LOGICAL k-slot = slot ^ ((c>>1)&3)
//     -> ds_read_b128 of a 16-lane column group spreads over 8 bank-groups
//        (2-way aliasing = free), and global_load_lds staging is a straight
//        linear copy.
//   col c -> n = g*1024 + ub*32 + wc*16 + cl  (g=(c>>4)&3, wc=c>>6, cl=c&15)
// ---------------------------------------------------------------------------
__global__ void pack_R(const float* __restrict__ R, bf16_t* __restrict__ Rp) {
    int idx = blockIdx.x * 256 + threadIdx.x;   // 4,194,304 total
    int e    = idx & 7;
    int slot = (idx >> 3) & 3;                  // physical 16B slot in 64B row
    int c    = (idx >> 5) & 127;
    int kb   = (idx >> 12) & 31;
    int ub   = idx >> 17;
    int g  = (c >> 4) & 3;
    int wc = c >> 6;
    int cl = c & 15;
    int n  = g * 1024 + ub * 32 + wc * 16 + cl;
    int k  = kb * 32 + ((slot ^ ((c >> 1) & 3)) << 3) + e;  // logical k
    Rp[idx] = (bf16_t)R[(size_t)k * 4096 + n];
}

// ---------------------------------------------------------------------------
// One LSTM step (round-0 base: per-step launch, p-pinned grid, c RMW global)
// with a DRAIN-FREE triple-buffered K-loop, BK=32, counted vmcnt:
//   per kb: [s_waitcnt vmcnt(6)]  (kb's 6 loads done; kb+1's 6 stay in flight)
//           [s_barrier]           (raw: no vm drain ever)
//           [STAGE(kb+2) -> buf (kb+2)%3]   (~2 iterations of latency cover)
//           [12 ds_read_b128 frags -> regs] [32 MFMA, setprio]
//   buffer (kb+2)%3 was read at iter kb-1 and provably consumed (lgkm waits
//   precede that iter's MFMAs) before any wave passes this iter's barrier.
//   Tail made uniform by wrap-staging (kb+2)&31 (12 dummy loads, harmless).
// LDS: A 3x8KB + B 3x2x8KB + lsX = 72.5 KB -> 2 blocks/CU kept.
// ---------------------------------------------------------------------------
__global__ __launch_bounds__(256, 2)
void lstm_step(const bf16_t* __restrict__ hin,
               bf16_t* __restrict__ hout,
               float* __restrict__ cst,
               const bf16_t* __restrict__ Rp,
               const float* __restrict__ Wx,     // (4096,)
               const float* __restrict__ bias,   // (4096,)
               const float* __restrict__ w1,     // (1024,)
               const float* __restrict__ b1,
               const float* __restrict__ w2,
               const float* __restrict__ b2,
               const float* __restrict__ inputs, // [4096,5]
               float* __restrict__ praw,         // 3*4096
               float* __restrict__ out,          // [4096,200]
               int t)
{
    __shared__ __align__(16) bf16_t lsA[3][4096];        // 24 KB
    __shared__ __align__(16) bf16_t lsB[3][2][4096];     // 48 KB
    __shared__ float lsX[128];

    const int tid  = threadIdx.x;
    const int wave = tid >> 6;
    const int lane = tid & 63;
    const int p    = blockIdx.x;   // 0..15 fastest -> panels pinned per XCD
    const int G    = blockIdx.y;   // 0..31
    const int l15  = lane & 15;
    const int quad = lane >> 4;
    const int rbase = (wave >> 1) * 64;
    const int wc    = wave & 1;
    // staging: lane writes phys slot (lane&3) of row base+(lane>>2);
    // logical slot there = (lane&3) ^ ((row>>1)&3) = (lane&3)^((lane>>3)&3)
    const int a_kk32 = (((lane & 3) ^ ((lane >> 3) & 3)) << 3);
    // frag read: phys slot = quad ^ ((row|c)>>1 & 3) = quad ^ ((l15>>1)&3)
    const int sw32   = ((quad ^ ((l15 >> 1) & 3)) << 3);

    float*       pr_acc  = praw + (size_t)(t % 3) * B_SZ;
    const float* pr_read = praw + (size_t)((t + 2) % 3) * B_SZ;
    float*       pr_zero = praw + (size_t)((t + 1) % 3) * B_SZ;

    const bf16_t* Ap  = hin + (size_t)G * 128 * U_SZ;
    const bf16_t* Bp0 = Rp + (size_t)(2 * p) * 131072;
    const bf16_t* Bp1 = Bp0 + 131072;

    // ---- prologue FIRST (its divergent VMEM ops retire before the stages,
    //      keeping the vmcnt(6) count exact: newest 6 = next kb's stage) ----
    if (tid < 128) {
        int row = G * 128 + tid;
        float x;
        if (t < SEQ) {
            x = inputs[row * SEQ + t];
        } else {
            float x1 = fmaxf(pr_read[row] + b1[0], 0.f);
            x = (t == SEQ) ? x1 : x1 * w2[0] + b2[0];
            if (p == 0) out[(size_t)row * TSTEPS + (t - SEQ)] = x;
        }
        lsX[tid] = x;
        if (p == 0) pr_zero[row] = 0.f;
    }

    // ---- stage helper: 6 uniform loads per wave (A:2, B:4) ----
    auto STAGE = [&](int ksrc, int buf) {
        #pragma unroll
        for (int i = 0; i < 2; ++i) {            // A: 8 KB, rows of 64 B
            int brow = i * 64 + wave * 16;       // wave-uniform base row
            LOAD_LDS16(Ap + (size_t)(brow + (lane >> 2)) * U_SZ
                          + ksrc * 32 + a_kk32,
                       &lsA[buf][brow * 32]);
        }
        #pragma unroll
        for (int i = 0; i < 2; ++i) {            // B: 2 x 8 KB straight copy
            int chunk = wave * 2 + i;
            LOAD_LDS16(Bp0 + (size_t)ksrc * 4096 + chunk * 512 + lane * 8,
                       &lsB[buf][0][chunk * 512]);
            LOAD_LDS16(Bp1 + (size_t)ksrc * 4096 + chunk * 512 + lane * 8,
                       &lsB[buf][1][chunk * 512]);
        }
    };

    STAGE(0, 0);
    STAGE(1, 1);

    // ---- drain-free pipelined K-loop (32 steps of BK=32) ----
    f32x4 acc[2][4][4] = {};
    int bi = 0;                                  // buffer of current kb

    for (int kb = 0; kb < 32; ++kb) {
        // wait current kb's 6 loads (leave next kb's 6 in flight), then sync
        asm volatile("s_waitcnt vmcnt(6)" ::: "memory");
        __builtin_amdgcn_sched_barrier(0);
        __builtin_amdgcn_s_barrier();
        __builtin_amdgcn_sched_barrier(0);

        // stage kb+2 into buffer (bi+2)%3 (read at iter kb-1, now free)
        int bs = bi + 2; if (bs >= 3) bs -= 3;
        STAGE((kb + 2) & 31, bs);

        // fragments -> registers (compiler inserts fine-grained lgkmcnt)
        bf16x8 af[4], bfr[2][4];
        #pragma unroll
        for (int mi = 0; mi < 4; ++mi)
            af[mi] = *(const bf16x8*)
                &lsA[bi][(rbase + mi * 16 + l15) * 32 + sw32];
        #pragma unroll
        for (int T = 0; T < 2; ++T)
            #pragma unroll
            for (int ni = 0; ni < 4; ++ni)
                bfr[T][ni] = *(const bf16x8*)
                    &lsB[bi][T][(wc * 64 + ni * 16 + l15) * 32 + sw32];

        __builtin_amdgcn_s_setprio(1);
        #pragma unroll
        for (int T = 0; T < 2; ++T)
            #pragma unroll
            for (int mi = 0; mi < 4; ++mi)
                #pragma unroll
                for (int ni = 0; ni < 4; ++ni)
                    acc[T][mi][ni] = __builtin_amdgcn_mfma_f32_16x16x32_bf16(
                        af[mi], bfr[T][ni], acc[T][mi][ni], 0, 0, 0);
        __builtin_amdgcn_s_setprio(0);

        bi = bi + 1; if (bi >= 3) bi = 0;
    }

    // ---- epilogue: gates, c RMW (global fp32), h write, pred partials ----
    int uu[2];
    uu[0] = (2 * p) * 32 + wc * 16 + l15;
    uu[1] = uu[0] + 32;
    float g_b[2][4], g_w[2][4], w1u[2];
    #pragma unroll
    for (int T = 0; T < 2; ++T) {
        #pragma unroll
        for (int g = 0; g < 4; ++g) {
            g_b[T][g] = bias[g * 1024 + uu[T]];
            g_w[T][g] = Wx[g * 1024 + uu[T]];
        }
        w1u[T] = w1[uu[T]];
    }
    const bool do_pred = (t >= SEQ - 1);

    #pragma unroll
    for (int mi = 0; mi < 4; ++mi) {
        #pragma unroll
        for (int r = 0; r < 4; ++r) {
            int rl   = rbase + mi * 16 + quad * 4 + r;
            int brow = G * 128 + rl;
            float xv = lsX[rl];
            float ps = 0.f;
            #pragma unroll
            for (int T = 0; T < 2; ++T) {
                float zi = acc[T][mi][0][r] + g_b[T][0] + xv * g_w[T][0];
                float zf = acc[T][mi][1][r] + g_b[T][1] + xv * g_w[T][1];
                float zg = acc[T][mi][2][r] + g_b[T][2] + xv * g_w[T][2];
                float zo = acc[T][mi][3][r] + g_b[T][3] + xv * g_w[T][3];
                float ig = fsig(zi), fg = fsig(zf);
                float gg = ftanh(zg), og = fsig(zo);
                size_t off = (size_t)brow * U_SZ + uu[T];
                float cn = fg * cst[off] + ig * gg;
                cst[off] = cn;
                float hv = og * ftanh(cn);
                hout[off] = (bf16_t)hv;
                ps += hv * w1u[T];
            }
            if (do_pred) {
                ps += __shfl_xor(ps, 1);
                ps += __shfl_xor(ps, 2);
                ps += __shfl_xor(ps, 4);
                ps += __shfl_xor(ps, 8);
                if (l15 == 0) atomicAdd(&pr_acc[brow], ps);
            }
        }
    }
}

// final output slot 199 from praw of step 203 (203 % 3 == 2)
__global__ void pred_final(const float* __restrict__ praw,
                           const float* __restrict__ b1,
                           const float* __restrict__ w2,
                           const float* __restrict__ b2,
                           float* __restrict__ out)
{
    int row = blockIdx.x * 256 + threadIdx.x;
    float x1 = fmaxf(praw[2 * B_SZ + row] + b1[0], 0.f);
    out[(size_t)row * TSTEPS + 199] = x1 * w2[0] + b2[0];
}

extern "C" void kernel_launch(void* const* d_in, const int* in_sizes, int n_in,
                              void* d_out, int out_size, void* d_ws, size_t ws_size,
                              hipStream_t stream) {
    const float* inputs = (const float*)d_in[0];   // [4096,5,1]
    const float* Wx     = (const float*)d_in[1];   // [1,4096]
    const float* R      = (const float*)d_in[2];   // [1024,4096]
    const float* bias   = (const float*)d_in[3];   // [4096]
    const float* w1     = (const float*)d_in[4];   // [1024,1]
    const float* b1     = (const float*)d_in[5];
    const float* w2     = (const float*)d_in[6];
    const float* b2     = (const float*)d_in[7];
    float* out = (float*)d_out;

    char* ws = (char*)d_ws;
    const size_t RP_BYTES = (size_t)32 * 131072 * 2;          // 8 MB
    const size_t H_BYTES  = (size_t)B_SZ * U_SZ * 2;          // 8 MB
    const size_t C_BYTES  = (size_t)B_SZ * U_SZ * 4;          // 16 MB
    bf16_t* Rp   = (bf16_t*)ws;                ws += RP_BYTES;
    bf16_t* h0   = (bf16_t*)ws;                ws += H_BYTES;
    bf16_t* h1   = (bf16_t*)ws;                ws += H_BYTES;
    float*  cbuf = (float*)ws;                 ws += C_BYTES;
    float*  praw = (float*)ws;                 ws += 3 * B_SZ * 4;
    bf16_t* hb[2] = {h0, h1};

    hipMemsetAsync(h0, 0, H_BYTES, stream);
    hipMemsetAsync(cbuf, 0, C_BYTES, stream);
    hipMemsetAsync(praw, 0, 3 * B_SZ * 4, stream);

    pack_R<<<16384, 256, 0, stream>>>(R, Rp);

    dim3 grid(16, 32);   // p fastest -> B panels pinned per XCD
    int cur = 0;
    for (int t = 0; t < STEPS; ++t) {
        lstm_step<<<grid, 256, 0, stream>>>(hb[cur], hb[1 - cur], cbuf, Rp,
                                            Wx, bias, w1, b1, w2, b2,
                                            inputs, praw, out, t);
        cur ^= 1;
    }
    pred_final<<<16, 256, 0, stream>>>(praw, b1, w2, b2, out);
}